// Round 11
// baseline (246.469 us; speedup 1.0000x reference)
//
#include <hip/hip_runtime.h>
#include <stdint.h>

typedef __bf16 bf16x8 __attribute__((ext_vector_type(8)));
typedef float  f32x4  __attribute__((ext_vector_type(4)));

#define ATTN_SCALE 2.7621359e-3f   // 1/(sqrt(128)*sqrt(1024))

__device__ __forceinline__ unsigned short f2bf(float f) {
  union { float f; uint32_t u; } v; v.f = f;
  uint32_t u = v.u;
  uint32_t r = (u + 0x7FFFu + ((u >> 16) & 1u)) >> 16;   // RNE
  return (unsigned short)r;
}

__device__ __forceinline__ void load_lds16(const unsigned short* g, unsigned short* l) {
  __builtin_amdgcn_global_load_lds(
      (const __attribute__((address_space(1))) void*)g,
      (__attribute__((address_space(3))) void*)l, 16, 0, 0);
}

__device__ __forceinline__ f32x4 mfma16(bf16x8 a, bf16x8 b, f32x4 c) {
  return __builtin_amdgcn_mfma_f32_16x16x32_bf16(a, b, c, 0, 0, 0);
}

__device__ __forceinline__ bf16x8 ones_bf16() {
  union { unsigned short u[8]; bf16x8 v; } c;
#pragma unroll
  for (int j = 0; j < 8; ++j) c.u[j] = 0x3F80;   // bf16 1.0
  return c.v;
}

// ---------------------------------------------------------------- QKV projection GEMM
// [frozen from round 8 - passed] 3-pass structure (768 blocks = 3/CU, 12 KB
// LDS) with weight conversion fused in: B reg-staged from f32 W via f2bf RNE
// -> ds_write_b128 (bit-identical to the old cvtw + global_load_lds path).
__global__ __launch_bounds__(256, 3) void k_proj(
    const float* __restrict__ X,             // [16384][1024] f32
    const float* __restrict__ Wq,            // [128][1024] f32
    const float* __restrict__ Wk,
    const float* __restrict__ Wv,
    unsigned short* __restrict__ Qb,         // [16384][128]
    unsigned short* __restrict__ Kb,         // [16384][128]
    unsigned short* __restrict__ Vt)         // [4][128][4096]
{
  __shared__ __align__(16) unsigned short sm[2048 + 4096];   // As[64][32] | Bs[128][32], 12 KB
  unsigned short* As = sm;
  unsigned short* Bs = sm + 2048;
  const int t = threadIdx.x;
  const int mtile = blockIdx.x;          // 0..255 (64 rows each)
  const int nt = blockIdx.y;             // 0..2  (Q, K, V weight)
  const int w = t >> 6, lane = t & 63, quad = lane >> 4, l15 = lane & 15;
  const int wm = w & 1, wn = w >> 1;

  const float* Wsel = (nt == 0) ? Wq : (nt == 1) ? Wk : Wv;

  const float* ag0 = X + (size_t)(mtile * 64 + (t >> 2)) * 1024 + (t & 3) * 8;
  const float* bg0 = Wsel + (size_t)(t >> 2) * 1024 + (t & 3) * 8;
  unsigned short* aw = &As[t * 8];       // == row(t>>2)*32 + (t&3)*8, linear in t
  unsigned short* bw = &Bs[t * 8];

  f32x4 acc[2][4] = {};

  // prologue: kt=0 A and B f32 loads in flight
  float4 a0 = *(const float4*)(ag0);
  float4 a1 = *(const float4*)(ag0 + 4);
  float4 b0 = *(const float4*)(bg0);
  float4 b1 = *(const float4*)(bg0 + 4);
  float4 b2 = *(const float4*)(bg0 + 65536);       // row +64
  float4 b3 = *(const float4*)(bg0 + 65536 + 4);

  for (int kt = 0; kt < 32; ++kt) {
    __syncthreads();                       // prior MFMA LDS reads done
    {
      union { unsigned short u[8]; uint4 v; } pa;
      pa.u[0] = f2bf(a0.x); pa.u[1] = f2bf(a0.y);
      pa.u[2] = f2bf(a0.z); pa.u[3] = f2bf(a0.w);
      pa.u[4] = f2bf(a1.x); pa.u[5] = f2bf(a1.y);
      pa.u[6] = f2bf(a1.z); pa.u[7] = f2bf(a1.w);
      *(uint4*)aw = pa.v;                  // ds_write_b128 (A row t>>2)
      union { unsigned short u[8]; uint4 v; } pb;
      pb.u[0] = f2bf(b0.x); pb.u[1] = f2bf(b0.y);
      pb.u[2] = f2bf(b0.z); pb.u[3] = f2bf(b0.w);
      pb.u[4] = f2bf(b1.x); pb.u[5] = f2bf(b1.y);
      pb.u[6] = f2bf(b1.z); pb.u[7] = f2bf(b1.w);
      *(uint4*)bw = pb.v;                  // B row t>>2
      pb.u[0] = f2bf(b2.x); pb.u[1] = f2bf(b2.y);
      pb.u[2] = f2bf(b2.z); pb.u[3] = f2bf(b2.w);
      pb.u[4] = f2bf(b3.x); pb.u[5] = f2bf(b3.y);
      pb.u[6] = f2bf(b3.z); pb.u[7] = f2bf(b3.w);
      *(uint4*)(bw + 2048) = pb.v;         // B row 64+(t>>2)
    }
    if (kt < 31) {                         // issue next-kt loads; covered by sync+MFMA
      a0 = *(const float4*)(ag0 + (kt + 1) * 32);
      a1 = *(const float4*)(ag0 + (kt + 1) * 32 + 4);
      b0 = *(const float4*)(bg0 + (kt + 1) * 32);
      b1 = *(const float4*)(bg0 + (kt + 1) * 32 + 4);
      b2 = *(const float4*)(bg0 + (kt + 1) * 32 + 65536);
      b3 = *(const float4*)(bg0 + (kt + 1) * 32 + 65536 + 4);
    }
    __syncthreads();                       // drains A/B ds_writes

    bf16x8 af[2], bfr[4];
#pragma unroll
    for (int i = 0; i < 2; ++i)
      af[i] = *(const bf16x8*)&As[(wm * 32 + i * 16 + l15) * 32 + quad * 8];
#pragma unroll
    for (int j = 0; j < 4; ++j)
      bfr[j] = *(const bf16x8*)&Bs[(wn * 64 + j * 16 + l15) * 32 + quad * 8];
#pragma unroll
    for (int i = 0; i < 2; ++i)
#pragma unroll
      for (int j = 0; j < 4; ++j)
        acc[i][j] = mfma16(af[i], bfr[j], acc[i][j]);
  }

  if (nt != 2) {
    const int m0 = mtile * 64 + wm * 32;
#pragma unroll
    for (int i = 0; i < 2; ++i)
#pragma unroll
      for (int j = 0; j < 4; ++j)
#pragma unroll
        for (int r = 0; r < 4; ++r) {
          int m = m0 + i * 16 + quad * 4 + r;
          int n = wn * 64 + j * 16 + l15;
          float v = acc[i][j][r];
          if (nt == 0) Qb[(size_t)m * 128 + n] = f2bf(v * ATTN_SCALE);
          else         Kb[(size_t)m * 128 + n] = f2bf(v);
        }
  } else {
    // transpose through LDS -> coalesced Vt writes
    // NOTE: jj loop MUST be fully unrolled (j indexes the acc register array;
    // runtime index demotes acc to scratch -> massive spill traffic).
    float* Ts = (float*)sm;                   // [64 m][17] f32 (4352 B)
    const int bb = mtile >> 6;
    const int s0 = (mtile & 63) * 64;
#pragma unroll
    for (int jj = 0; jj < 8; ++jj) {
      __syncthreads();
      if (wn == (jj >> 2)) {
        const int j = jj & 3;
#pragma unroll
        for (int i = 0; i < 2; ++i)
#pragma unroll
          for (int r = 0; r < 4; ++r)
            Ts[(wm * 32 + i * 16 + quad * 4 + r) * 17 + l15] = acc[i][j][r];
      }
      __syncthreads();
      int n2 = jj * 16 + (t >> 4);            // d index within this 16-col chunk
      int m2 = (t & 15) * 4;                  // 4 seq rows per thread
      union { unsigned short u[4]; uint2 v; } pk;
#pragma unroll
      for (int e = 0; e < 4; ++e) pk.u[e] = f2bf(Ts[(m2 + e) * 17 + (t >> 4)]);
      *(uint2*)&Vt[((size_t)(bb * 128 + n2)) * 4096 + s0 + m2] = pk.v;
    }
  }
}

// ---------------------------------------------------------------- flash attention
// v9: V-direct-from-L2, attempt 3 -- with HARD scheduling control.
// Rounds 9 and 10 produced IDENTICAL counters (MfmaUtil 14.5, VGPR 84) despite
// opposite source-level issue orders of {V reg-loads, K prefetch}: the
// compiler's scheduler chose its own emission order both times, so the K
// prefetch kept entering the vmem FIFO where PV's wait on vfr drained it ->
// full L2 latency exposed per iteration. Fix per guide rules #18/#19:
// __builtin_amdgcn_sched_barrier(0) fences pin the post-barrier block to
//   [8 x V global_load -> regs]  SB(0)  [4 x K global_load_lds]  SB(0)
// so V loads are strictly OLDEST in the FIFO; the compiler's dependence-
// tracked wait before PV then retires only V (>= vmcnt(4)), K stays in
// flight with softmax+PV+next-alpha as cover. SB(0) also placed after the
// P lgkmcnt(0) (rule #18: MFMA can hoist past inline-asm lgkm waits).
// Intent unchanged from r8->r9: V out of LDS (-32KB/block-iter LDS traffic),
// no beta barrier (P wave-private), K double-buffered, ONE barrier + ONE
// vmcnt(0) per iter. Numerics bit-identical throughout.
__global__ __launch_bounds__(256, 3) void k_flash(
    const unsigned short* __restrict__ Qb,   // [4][4096][128] bf16, pre-scaled
    const unsigned short* __restrict__ Kb,   // [4][4096][128] bf16
    const unsigned short* __restrict__ Vt,   // [4][128][4096] bf16
    float* __restrict__ Om,                  // [2][16384][128] f32 partials
    float* __restrict__ lp)                  // [2][16384] row sums
{
  __shared__ __align__(16) unsigned short smem[21504];   // 43008 B
  // K0 [0,8192) | K1 [8192,16384) | P [16384,21504)
  unsigned short* Psh = smem + 16384;    // per-wave [32 q][stride 40]
  float* Ob  = (float*)smem;             // epilogue overlay [64][128] f32 (over K bufs)
  float* lsh = (float*)(smem + 16384);   // epilogue overlay [64] f32 (over P)

  const int t = threadIdx.x;
  const int w = t >> 6, lane = t & 63, quad = lane >> 4, l15 = lane & 15;
  const int h = w & 1, p = w >> 1;
  // XCD-affine decode: xcd = bid & 7; pair (2b, 2b+1) = batch b; even XCD of
  // the pair gets keys 0..2047 (sp=0), odd 2048..4095. K/V ~1 MB per XCD L2.
  const int bid = blockIdx.x;            // 0..511
  const int b   = (bid & 7) >> 1;
  const int sp  = bid & 1;
  const int qt  = bid >> 3;              // 0..63

  const unsigned short* Qg = Qb + (size_t)(b * 4096 + qt * 64 + h * 32) * 128;
  const unsigned short* Kg = Kb + (size_t)b * 4096 * 128;
  const unsigned short* Vg = Vt + (size_t)b * 128 * 4096;

  bf16x8 qf[2][4];
#pragma unroll
  for (int mt = 0; mt < 2; ++mt)
#pragma unroll
    for (int kk = 0; kk < 4; ++kk)
      qf[mt][kk] = *(const bf16x8*)&Qg[(size_t)(mt * 16 + l15) * 128 + kk * 32 + quad * 8];

  f32x4 O[2][8] = {};
  f32x4 Ol[2] = {};

  // K staging map (chunk-XOR swizzled on the fetch side, as before):
  const unsigned short* kg0 = Kg + (size_t)(t >> 4) * 128 + (((t & 15) ^ ((t >> 5) & 7)) * 8);
  // V direct-read pointer: lane(l15,quad) -> d-row l15 (+dt*16),
  // key chunk (p*4+quad)*8; advances 64 keys per iteration (loop-carried).
  const unsigned short* vptr = Vg + (size_t)l15 * 4096 + (p * 4 + quad) * 8
                                  + (size_t)(sp * 32) * 64;

  const int kt0 = sp * 32;

  // prologue: K(kt0) -> K0
  {
    const unsigned short* kg = kg0 + (size_t)kt0 * 8192;
    unsigned short* kw = &smem[w * 512];
#pragma unroll
    for (int it = 0; it < 4; ++it)
      load_lds16(kg + it * 2048, kw + it * 2048);
  }

  for (int i = 0; i < 32; ++i) {
    const int cur = i & 1, nxt = cur ^ 1;
    const int ktn = (i < 31) ? (kt0 + i + 1) : kt0;   // wrap dummy on last iter

    // alpha (the ONLY barrier per iter): K[cur] resident (the 4 K loads are
    // the only outstanding vmem; V regs of iter i-1 were retired before PV).
    // Barrier also certifies all waves finished QK(i-1) -> buf[nxt] free.
    asm volatile("s_waitcnt vmcnt(0)" ::: "memory");
    asm volatile("s_barrier" ::: "memory");

    // (1) V fragments -> registers, PINNED oldest in the vmem FIFO.
    bf16x8 vfr[8];
#pragma unroll
    for (int dt = 0; dt < 8; ++dt)
      vfr[dt] = *(const bf16x8*)&vptr[(size_t)dt * 65536];
    __builtin_amdgcn_sched_barrier(0);   // V loads may not move past this

    // (2) K[ktn] -> buf[nxt], strictly AFTER the V loads in the FIFO.
    {
      const unsigned short* kg = kg0 + (size_t)ktn * 8192;
      unsigned short* kw = &smem[nxt * 8192 + w * 512];
#pragma unroll
      for (int it = 0; it < 4; ++it)
        load_lds16(kg + it * 2048, kw + it * 2048);
    }
    __builtin_amdgcn_sched_barrier(0);   // K prefetch may not sink below

    // S = Q K^T on K[cur] (keys paired even/odd: lane l15 holds
    // keys p*32 + 2*l15 + ntk)
    const unsigned short* Kshc = &smem[cur * 8192];
    f32x4 sc[2][2] = {};
#pragma unroll
    for (int ntk = 0; ntk < 2; ++ntk) {
      const int row = p * 32 + 2 * l15 + ntk;
#pragma unroll
      for (int kk = 0; kk < 4; ++kk) {
        bf16x8 kf = *(const bf16x8*)&Kshc[row * 128 + (((kk * 4 + quad) ^ (l15 & 7)) * 8)];
        sc[0][ntk] = mfma16(qf[0][kk], kf, sc[0][ntk]);
        sc[1][ntk] = mfma16(qf[1][kk], kf, sc[1][ntk]);
      }
    }

    // P = exp(S) (no max shift), packed pair writes (keys 2*l15, 2*l15+1)
#pragma unroll
    for (int mt = 0; mt < 2; ++mt)
#pragma unroll
      for (int r = 0; r < 4; ++r) {
        float e0 = __expf(sc[mt][0][r]);
        float e1 = __expf(sc[mt][1][r]);
        int row = mt * 16 + quad * 4 + r;
        uint32_t pk = (uint32_t)f2bf(e0) | ((uint32_t)f2bf(e1) << 16);
        *(uint32_t*)&Psh[w * 1280 + row * 40 + 2 * l15] = pk;
      }

    // P roundtrip is wave-private: no barrier, just drain own LDS ops.
    // SB(0): forbid hoisting the P-read MFMAs above this wait (rule #18).
    asm volatile("s_waitcnt lgkmcnt(0)" ::: "memory");
    __builtin_amdgcn_sched_barrier(0);

    bf16x8 pf0 = *(const bf16x8*)&Psh[w * 1280 + l15 * 40 + quad * 8];
    bf16x8 pf1 = *(const bf16x8*)&Psh[w * 1280 + (16 + l15) * 40 + quad * 8];
    const bf16x8 one = ones_bf16();
    Ol[0] = mfma16(pf0, one, Ol[0]);     // row-sums of P (free l accumulate)
    Ol[1] = mfma16(pf1, one, Ol[1]);
#pragma unroll
    for (int dt = 0; dt < 8; ++dt) {
      O[0][dt] = mfma16(pf0, vfr[dt], O[0][dt]);
      O[1][dt] = mfma16(pf1, vfr[dt], O[1][dt]);
    }

    vptr += 64;                          // next 64-key tile
  }

  // ---- merge the two key-half partials (additive: no max state) ----
  // __syncthreads drains vmcnt(0) (wrap-dummy K prefetch lands BEFORE the
  // overlay writes below) + lgkmcnt, then barrier.
  __syncthreads();
  if (p == 1) {
#pragma unroll
    for (int mt = 0; mt < 2; ++mt)
#pragma unroll
      for (int r = 0; r < 4; ++r) {
        int row = h * 32 + mt * 16 + quad * 4 + r;
        if (l15 == 0) lsh[row] = Ol[mt][r];
#pragma unroll
        for (int dt = 0; dt < 8; ++dt)
          Ob[row * 128 + dt * 16 + l15] = O[mt][dt][r];
      }
  }
  __syncthreads();
  if (p == 0) {
    const size_t rowbase = (size_t)b * 4096 + qt * 64;
    float* Omp = Om + (size_t)sp * 2097152;
#pragma unroll
    for (int mt = 0; mt < 2; ++mt)
#pragma unroll
      for (int r = 0; r < 4; ++r) {
        int row = h * 32 + mt * 16 + quad * 4 + r;
#pragma unroll
        for (int dt = 0; dt < 8; ++dt)
          Omp[(rowbase + row) * 128 + dt * 16 + l15] =
              O[mt][dt][r] + Ob[row * 128 + dt * 16 + l15];
        if (l15 == 0)
          lp[(size_t)sp * 16384 + rowbase + row] = Ol[mt][r] + lsh[row];
      }
  }
}

// ---------------------------------------------------------------- merge key-splits
__global__ __launch_bounds__(256) void k_merge(const float* __restrict__ Om,
                                               const float* __restrict__ lp,
                                               float* __restrict__ out) {
  int i = blockIdx.x * 256 + threadIdx.x;   // float4 index, 524288 total
  int row = i >> 5;
  float inv = 1.0f / (lp[row] + lp[16384 + row]);
  float4 a = ((const float4*)Om)[i];
  float4 c = ((const float4*)Om)[524288 + i];
  float4 o;
  o.x = (a.x + c.x) * inv;
  o.y = (a.y + c.y) * inv;
  o.z = (a.z + c.z) * inv;
  o.w = (a.w + c.w) * inv;
  ((float4*)out)[i] = o;
}

// ---------------------------------------------------------------- launch
extern "C" void kernel_launch(void* const* d_in, const int* in_sizes, int n_in,
                              void* d_out, int out_size, void* d_ws, size_t ws_size,
                              hipStream_t stream) {
  const float* x  = (const float*)d_in[0];   // [4,4096,1024]
  const float* Wq = (const float*)d_in[1];   // [128,1024]
  const float* Wk = (const float*)d_in[2];
  const float* Wv = (const float*)d_in[3];
  float* out = (float*)d_out;                // [4,4096,128]

  unsigned short* ws  = (unsigned short*)d_ws;
  unsigned short* Qb  = ws;                   // 2,097,152 ush
  unsigned short* Kb  = Qb + 2097152;
  unsigned short* Vt  = Kb + 2097152;         // 2,097,152
  float* Om = (float*)(Vt + 2097152);         // 2*16384*128 f32
  float* lp = Om + 4194304;                   // 2*16384 f32

  k_proj<<<dim3(256, 3), 256, 0, stream>>>(x, Wq, Wk, Wv, Qb, Kb, Vt);
  k_flash<<<512, 256, 0, stream>>>(Qb, Kb, Vt, Om, lp);
  k_merge<<<2048, 256, 0, stream>>>(Om, lp, out);
}

// Round 12
// 175.583 us; speedup vs baseline: 1.4037x; 1.4037x over previous
//
#include <hip/hip_runtime.h>
#include <stdint.h>

typedef __bf16 bf16x8 __attribute__((ext_vector_type(8)));
typedef float  f32x4  __attribute__((ext_vector_type(4)));

#define ATTN_SCALE 2.7621359e-3f   // 1/(sqrt(128)*sqrt(1024))

__device__ __forceinline__ unsigned short f2bf(float f) {
  union { float f; uint32_t u; } v; v.f = f;
  uint32_t u = v.u;
  uint32_t r = (u + 0x7FFFu + ((u >> 16) & 1u)) >> 16;   // RNE
  return (unsigned short)r;
}

__device__ __forceinline__ void load_lds16(const unsigned short* g, unsigned short* l) {
  __builtin_amdgcn_global_load_lds(
      (const __attribute__((address_space(1))) void*)g,
      (__attribute__((address_space(3))) void*)l, 16, 0, 0);
}

__device__ __forceinline__ f32x4 mfma16(bf16x8 a, bf16x8 b, f32x4 c) {
  return __builtin_amdgcn_mfma_f32_16x16x32_bf16(a, b, c, 0, 0, 0);
}

__device__ __forceinline__ bf16x8 ones_bf16() {
  union { unsigned short u[8]; bf16x8 v; } c;
#pragma unroll
  for (int j = 0; j < 8; ++j) c.u[j] = 0x3F80;   // bf16 1.0
  return c.v;
}

// ---------------------------------------------------------------- QKV projection GEMM
// v6: same 3-pass structure as round 8 (768 blocks = 3/CU, 12 KB LDS, W-cvt
// fused) with the BARRIER DRAIN removed. Round-8's __syncthreads compiles to
// "s_waitcnt vmcnt(0) lgkmcnt(0); s_barrier" (guide §5) -> the next-kt f32
// loads issued just before it were retired AT the barrier: the software
// pipeline never existed, each of the 32 k-steps ate a full L3/HBM latency.
// Fix: (a) raw "lgkmcnt(0); s_barrier" pairs (LDS hazards still ordered;
// global loads stay in flight across barriers - flash's proven pattern);
// (b) kt+1 loads issued at the TOP of the body into ping-pong registers,
// consumed next iteration (cover = cvt + bar + MFMA + bar). No vmcnt is ever
// needed at a barrier (no global_load_lds here; the compiler's tracked
// vmcnt(N) before the conversion is the only wait). Numerics bit-identical.
__global__ __launch_bounds__(256, 3) void k_proj(
    const float* __restrict__ X,             // [16384][1024] f32
    const float* __restrict__ Wq,            // [128][1024] f32
    const float* __restrict__ Wk,
    const float* __restrict__ Wv,
    unsigned short* __restrict__ Qb,         // [16384][128]
    unsigned short* __restrict__ Kb,         // [16384][128]
    unsigned short* __restrict__ Vt)         // [4][128][4096]
{
  __shared__ __align__(16) unsigned short sm[2048 + 4096];   // As[64][32] | Bs[128][32], 12 KB
  unsigned short* As = sm;
  unsigned short* Bs = sm + 2048;
  const int t = threadIdx.x;
  const int mtile = blockIdx.x;          // 0..255 (64 rows each)
  const int nt = blockIdx.y;             // 0..2  (Q, K, V weight)
  const int w = t >> 6, lane = t & 63, quad = lane >> 4, l15 = lane & 15;
  const int wm = w & 1, wn = w >> 1;

  const float* Wsel = (nt == 0) ? Wq : (nt == 1) ? Wk : Wv;

  const float* ag0 = X + (size_t)(mtile * 64 + (t >> 2)) * 1024 + (t & 3) * 8;
  const float* bg0 = Wsel + (size_t)(t >> 2) * 1024 + (t & 3) * 8;
  unsigned short* aw = &As[t * 8];       // == row(t>>2)*32 + (t&3)*8, linear in t
  unsigned short* bw = &Bs[t * 8];

  f32x4 acc[2][4] = {};

  // prologue: kt=0 A and B f32 loads -> current regs
  float4 a0 = *(const float4*)(ag0);
  float4 a1 = *(const float4*)(ag0 + 4);
  float4 b0 = *(const float4*)(bg0);
  float4 b1 = *(const float4*)(bg0 + 4);
  float4 b2 = *(const float4*)(bg0 + 65536);       // row +64
  float4 b3 = *(const float4*)(bg0 + 65536 + 4);

  for (int kt = 0; kt < 32; ++kt) {
    // raw barrier 1: own LDS ops (prev-iter MFMA ds_reads) drained, then
    // rendezvous -> As/Bs free to overwrite. Global loads stay in flight.
    asm volatile("s_waitcnt lgkmcnt(0)" ::: "memory");
    asm volatile("s_barrier" ::: "memory");

    // issue kt+1 loads FIRST (ping-pong regs, consumed next iteration; the
    // conversion below gives the compiler's vmcnt wait a full body of cover)
    float4 na0 = a0, na1 = a1, nb0 = b0, nb1 = b1, nb2 = b2, nb3 = b3;
    if (kt < 31) {
      na0 = *(const float4*)(ag0 + (kt + 1) * 32);
      na1 = *(const float4*)(ag0 + (kt + 1) * 32 + 4);
      nb0 = *(const float4*)(bg0 + (kt + 1) * 32);
      nb1 = *(const float4*)(bg0 + (kt + 1) * 32 + 4);
      nb2 = *(const float4*)(bg0 + (kt + 1) * 32 + 65536);
      nb3 = *(const float4*)(bg0 + (kt + 1) * 32 + 65536 + 4);
    }

    // convert current kt (loaded one iter ago) -> LDS
    {
      union { unsigned short u[8]; uint4 v; } pa;
      pa.u[0] = f2bf(a0.x); pa.u[1] = f2bf(a0.y);
      pa.u[2] = f2bf(a0.z); pa.u[3] = f2bf(a0.w);
      pa.u[4] = f2bf(a1.x); pa.u[5] = f2bf(a1.y);
      pa.u[6] = f2bf(a1.z); pa.u[7] = f2bf(a1.w);
      *(uint4*)aw = pa.v;                  // ds_write_b128 (A row t>>2)
      union { unsigned short u[8]; uint4 v; } pb;
      pb.u[0] = f2bf(b0.x); pb.u[1] = f2bf(b0.y);
      pb.u[2] = f2bf(b0.z); pb.u[3] = f2bf(b0.w);
      pb.u[4] = f2bf(b1.x); pb.u[5] = f2bf(b1.y);
      pb.u[6] = f2bf(b1.z); pb.u[7] = f2bf(b1.w);
      *(uint4*)bw = pb.v;                  // B row t>>2
      pb.u[0] = f2bf(b2.x); pb.u[1] = f2bf(b2.y);
      pb.u[2] = f2bf(b2.z); pb.u[3] = f2bf(b2.w);
      pb.u[4] = f2bf(b3.x); pb.u[5] = f2bf(b3.y);
      pb.u[6] = f2bf(b3.z); pb.u[7] = f2bf(b3.w);
      *(uint4*)(bw + 2048) = pb.v;         // B row 64+(t>>2)
    }

    // raw barrier 2: own ds_writes committed, rendezvous -> tile readable.
    // kt+1 global loads remain in flight (the whole point).
    asm volatile("s_waitcnt lgkmcnt(0)" ::: "memory");
    asm volatile("s_barrier" ::: "memory");

    bf16x8 af[2], bfr[4];
#pragma unroll
    for (int i = 0; i < 2; ++i)
      af[i] = *(const bf16x8*)&As[(wm * 32 + i * 16 + l15) * 32 + quad * 8];
#pragma unroll
    for (int j = 0; j < 4; ++j)
      bfr[j] = *(const bf16x8*)&Bs[(wn * 64 + j * 16 + l15) * 32 + quad * 8];
#pragma unroll
    for (int i = 0; i < 2; ++i)
#pragma unroll
      for (int j = 0; j < 4; ++j)
        acc[i][j] = mfma16(af[i], bfr[j], acc[i][j]);

    a0 = na0; a1 = na1; b0 = nb0; b1 = nb1; b2 = nb2; b3 = nb3;
  }

  if (nt != 2) {
    const int m0 = mtile * 64 + wm * 32;
#pragma unroll
    for (int i = 0; i < 2; ++i)
#pragma unroll
      for (int j = 0; j < 4; ++j)
#pragma unroll
        for (int r = 0; r < 4; ++r) {
          int m = m0 + i * 16 + quad * 4 + r;
          int n = wn * 64 + j * 16 + l15;
          float v = acc[i][j][r];
          if (nt == 0) Qb[(size_t)m * 128 + n] = f2bf(v * ATTN_SCALE);
          else         Kb[(size_t)m * 128 + n] = f2bf(v);
        }
  } else {
    // transpose through LDS -> coalesced Vt writes
    // NOTE: jj loop MUST be fully unrolled (j indexes the acc register array;
    // runtime index demotes acc to scratch -> massive spill traffic).
    float* Ts = (float*)sm;                   // [64 m][17] f32 (4352 B)
    const int bb = mtile >> 6;
    const int s0 = (mtile & 63) * 64;
#pragma unroll
    for (int jj = 0; jj < 8; ++jj) {
      __syncthreads();
      if (wn == (jj >> 2)) {
        const int j = jj & 3;
#pragma unroll
        for (int i = 0; i < 2; ++i)
#pragma unroll
          for (int r = 0; r < 4; ++r)
            Ts[(wm * 32 + i * 16 + quad * 4 + r) * 17 + l15] = acc[i][j][r];
      }
      __syncthreads();
      int n2 = jj * 16 + (t >> 4);            // d index within this 16-col chunk
      int m2 = (t & 15) * 4;                  // 4 seq rows per thread
      union { unsigned short u[4]; uint2 v; } pk;
#pragma unroll
      for (int e = 0; e < 4; ++e) pk.u[e] = f2bf(Ts[(m2 + e) * 17 + (t >> 4)]);
      *(uint2*)&Vt[((size_t)(bb * 128 + n2)) * 4096 + s0 + m2] = pk.v;
    }
  }
}

// ---------------------------------------------------------------- flash attention
// Byte-exact round-8 kernel (56.9 us, passed; the measured optimum across 6
// schedule variants: K/V-dbuf, counted vmcnt, occupancy 8->12 waves, XCD
// affinity, phase-stagger, V-direct x3 -- all null or worse). Single-buffer
// K and V, 43008 B LDS, split=2, 512 blocks, XCD-affine decode (FETCH -4.3x),
// alpha/beta raw-barrier loop. Numerics bit-identical since round 0.
__global__ __launch_bounds__(256, 3) void k_flash(
    const unsigned short* __restrict__ Qb,   // [4][4096][128] bf16, pre-scaled
    const unsigned short* __restrict__ Kb,   // [4][4096][128] bf16
    const unsigned short* __restrict__ Vt,   // [4][128][4096] bf16
    float* __restrict__ Om,                  // [2][16384][128] f32 partials
    float* __restrict__ lp)                  // [2][16384] row sums
{
  __shared__ __align__(16) unsigned short smem[21504];   // 43008 B
  // K [0,8192) | V [8192,16384) | P [16384,21504)
  unsigned short* Psh = smem + 16384;    // per-wave [32 q][stride 40]
  float* Ob  = (float*)smem;             // epilogue overlay [64][128] f32 (over K+V)
  float* lsh = (float*)(smem + 16384);   // epilogue overlay [64] f32 (over P)

  const int t = threadIdx.x;
  const int w = t >> 6, lane = t & 63, quad = lane >> 4, l15 = lane & 15;
  const int h = w & 1, p = w >> 1;
  // XCD-affine decode: xcd = bid & 7; pair (2b, 2b+1) = batch b; even XCD of
  // the pair gets keys 0..2047 (sp=0), odd 2048..4095. K/V ~1 MB per XCD L2.
  const int bid = blockIdx.x;            // 0..511
  const int b   = (bid & 7) >> 1;
  const int sp  = bid & 1;
  const int qt  = bid >> 3;              // 0..63

  const unsigned short* Qg = Qb + (size_t)(b * 4096 + qt * 64 + h * 32) * 128;
  const unsigned short* Kg = Kb + (size_t)b * 4096 * 128;
  const unsigned short* Vg = Vt + (size_t)b * 128 * 4096;

  bf16x8 qf[2][4];
#pragma unroll
  for (int mt = 0; mt < 2; ++mt)
#pragma unroll
    for (int kk = 0; kk < 4; ++kk)
      qf[mt][kk] = *(const bf16x8*)&Qg[(size_t)(mt * 16 + l15) * 128 + kk * 32 + quad * 8];

  f32x4 O[2][8] = {};
  f32x4 Ol[2] = {};

  // staging maps (chunk-XOR swizzled on the fetch side):
  // K rows are read as row = 2*l15+ntk, so swizzle granularity is (row>>1)&7.
  const unsigned short* kg0 = Kg + (size_t)(t >> 4) * 128 + (((t & 15) ^ ((t >> 5) & 7)) * 8);
  const unsigned short* vg0 = Vg + (size_t)(t >> 3) * 4096 + (((t & 7) ^ ((t >> 3) & 7)) * 8);
  unsigned short* kw = &smem[w * 512];
  unsigned short* vw = &smem[8192 + w * 512];

  const int kt0 = sp * 32;

  // prologue: K(kt0) -> K buf (V issued inside the loop after alpha)
  {
    const unsigned short* kg = kg0 + (size_t)kt0 * 8192;
#pragma unroll
    for (int it = 0; it < 4; ++it)
      load_lds16(kg + it * 2048, kw + it * 2048);
  }

  for (int i = 0; i < 32; ++i) {
    const int kt = kt0 + i;
    const int ktn = (i < 31) ? (kt + 1) : kt0;   // wrap dummy on last iter

    // alpha: K[kt] resident (own loads retired + barrier covers all waves).
    // All PV(i-1) V-reads retired (data-dep before each wave's barrier).
    asm volatile("s_waitcnt vmcnt(0)" ::: "memory");
    asm volatile("s_barrier" ::: "memory");

    // issue V[kt] -> V buf (single; safe per above). Covered by QK+softmax.
    {
      const unsigned short* vg = vg0 + (size_t)kt * 64;
#pragma unroll
      for (int it = 0; it < 4; ++it)
        load_lds16(vg + (size_t)it * 131072, vw + it * 2048);
    }

    // S = Q K^T on K buf (keys paired even/odd: lane l15 holds
    // keys p*32 + 2*l15 + ntk)
    f32x4 sc[2][2] = {};
#pragma unroll
    for (int ntk = 0; ntk < 2; ++ntk) {
      const int row = p * 32 + 2 * l15 + ntk;
#pragma unroll
      for (int kk = 0; kk < 4; ++kk) {
        bf16x8 kf = *(const bf16x8*)&smem[row * 128 + (((kk * 4 + quad) ^ (l15 & 7)) * 8)];
        sc[0][ntk] = mfma16(qf[0][kk], kf, sc[0][ntk]);
        sc[1][ntk] = mfma16(qf[1][kk], kf, sc[1][ntk]);
      }
    }

    // P = exp(S) (no max shift), packed pair writes (keys 2*l15, 2*l15+1)
#pragma unroll
    for (int mt = 0; mt < 2; ++mt)
#pragma unroll
      for (int r = 0; r < 4; ++r) {
        float e0 = __expf(sc[mt][0][r]);
        float e1 = __expf(sc[mt][1][r]);
        int row = mt * 16 + quad * 4 + r;
        uint32_t pk = (uint32_t)f2bf(e0) | ((uint32_t)f2bf(e1) << 16);
        *(uint32_t*)&Psh[w * 1280 + row * 40 + 2 * l15] = pk;
      }

    // beta: V[kt] resident (own V loads are the only outstanding vmem) +
    // own P visible; barrier -> everyone's V resident, all QK reads done.
    asm volatile("s_waitcnt vmcnt(0) lgkmcnt(0)" ::: "memory");
    asm volatile("s_barrier" ::: "memory");

    // issue K[kt+1] -> K buf (free: all QK(i) reads retired). Covered by PV.
    {
      const unsigned short* kg = kg0 + (size_t)ktn * 8192;
#pragma unroll
      for (int it = 0; it < 4; ++it)
        load_lds16(kg + it * 2048, kw + it * 2048);
    }

    bf16x8 pf0 = *(const bf16x8*)&Psh[w * 1280 + l15 * 40 + quad * 8];
    bf16x8 pf1 = *(const bf16x8*)&Psh[w * 1280 + (16 + l15) * 40 + quad * 8];
    const bf16x8 one = ones_bf16();
    Ol[0] = mfma16(pf0, one, Ol[0]);     // row-sums of P (free l accumulate)
    Ol[1] = mfma16(pf1, one, Ol[1]);
    const unsigned short* Vshc = &smem[8192];
#pragma unroll
    for (int dt = 0; dt < 8; ++dt) {
      bf16x8 vf = *(const bf16x8*)&Vshc[(dt * 16 + l15) * 64 + (((p * 4 + quad) ^ (l15 & 7)) * 8)];
      O[0][dt] = mfma16(pf0, vf, O[0][dt]);
      O[1][dt] = mfma16(pf1, vf, O[1][dt]);
    }
  }

  // ---- merge the two key-half partials (additive: no max state) ----
  // __syncthreads drains vmcnt(0) (wrap-dummy K prefetch lands BEFORE the
  // overlay writes below) + lgkmcnt, then barrier.
  __syncthreads();
  if (p == 1) {
#pragma unroll
    for (int mt = 0; mt < 2; ++mt)
#pragma unroll
      for (int r = 0; r < 4; ++r) {
        int row = h * 32 + mt * 16 + quad * 4 + r;
        if (l15 == 0) lsh[row] = Ol[mt][r];
#pragma unroll
        for (int dt = 0; dt < 8; ++dt)
          Ob[row * 128 + dt * 16 + l15] = O[mt][dt][r];
      }
  }
  __syncthreads();
  if (p == 0) {
    const size_t rowbase = (size_t)b * 4096 + qt * 64;
    float* Omp = Om + (size_t)sp * 2097152;
#pragma unroll
    for (int mt = 0; mt < 2; ++mt)
#pragma unroll
      for (int r = 0; r < 4; ++r) {
        int row = h * 32 + mt * 16 + quad * 4 + r;
#pragma unroll
        for (int dt = 0; dt < 8; ++dt)
          Omp[(rowbase + row) * 128 + dt * 16 + l15] =
              O[mt][dt][r] + Ob[row * 128 + dt * 16 + l15];
        if (l15 == 0)
          lp[(size_t)sp * 16384 + rowbase + row] = Ol[mt][r] + lsh[row];
      }
  }
}

// ---------------------------------------------------------------- merge key-splits
__global__ __launch_bounds__(256) void k_merge(const float* __restrict__ Om,
                                               const float* __restrict__ lp,
                                               float* __restrict__ out) {
  int i = blockIdx.x * 256 + threadIdx.x;   // float4 index, 524288 total
  int row = i >> 5;
  float inv = 1.0f / (lp[row] + lp[16384 + row]);
  float4 a = ((const float4*)Om)[i];
  float4 c = ((const float4*)Om)[524288 + i];
  float4 o;
  o.x = (a.x + c.x) * inv;
  o.y = (a.y + c.y) * inv;
  o.z = (a.z + c.z) * inv;
  o.w = (a.w + c.w) * inv;
  ((float4*)out)[i] = o;
}

// ---------------------------------------------------------------- launch
extern "C" void kernel_launch(void* const* d_in, const int* in_sizes, int n_in,
                              void* d_out, int out_size, void* d_ws, size_t ws_size,
                              hipStream_t stream) {
  const float* x  = (const float*)d_in[0];   // [4,4096,1024]
  const float* Wq = (const float*)d_in[1];   // [128,1024]
  const float* Wk = (const float*)d_in[2];
  const float* Wv = (const float*)d_in[3];
  float* out = (float*)d_out;                // [4,4096,128]

  unsigned short* ws  = (unsigned short*)d_ws;
  unsigned short* Qb  = ws;                   // 2,097,152 ush
  unsigned short* Kb  = Qb + 2097152;
  unsigned short* Vt  = Kb + 2097152;         // 2,097,152
  float* Om = (float*)(Vt + 2097152);         // 2*16384*128 f32
  float* lp = Om + 4194304;                   // 2*16384 f32

  k_proj<<<dim3(256, 3), 256, 0, stream>>>(x, Wq, Wk, Wv, Qb, Kb, Vt);
  k_flash<<<512, 256, 0, stream>>>(Qb, Kb, Vt, Om, lp);
  k_merge<<<2048, 256, 0, stream>>>(Om, lp, out);
}